// Round 1
// baseline (258.022 us; speedup 1.0000x reference)
//
#include <hip/hip_runtime.h>
#include <stdint.h>
#include <math.h>

#define B_N 512
#define M_N 65536
#define D_N 256
#define C_N 10
#define TEMP_INV 14.285714285714286f   // 1/0.07
#define LOG2E_F 1.4426950408889634f
#define K2C (LOG2E_F * TEMP_INV)       // log2(e)/T : exp(x/T) = exp2(x*K2C)

typedef __attribute__((ext_vector_type(8))) __bf16 bf16x8;
typedef __attribute__((ext_vector_type(4))) float f32x4;

__device__ __forceinline__ unsigned short f2bf(float f) {
  unsigned int u = __float_as_uint(f);
  return (unsigned short)((u + 0x7FFFu + ((u >> 16) & 1u)) >> 16);  // RNE
}

__device__ __forceinline__ float wave_reduce_sum(float v) {
  v += __shfl_xor(v, 32, 64);
  v += __shfl_xor(v, 16, 64);
  v += __shfl_xor(v, 8, 64);
  v += __shfl_xor(v, 4, 64);
  v += __shfl_xor(v, 2, 64);
  v += __shfl_xor(v, 1, 64);
  return v;
}

// K1: normalize pro_memory rows -> bf16; accumulate per-class sum vectors and counts.
// grid 256 blocks x 256 threads; each wave handles 64 consecutive rows.
__global__ __launch_bounds__(256) void k_pro_norm(const float* __restrict__ pm,
                                                  const int* __restrict__ pl,
                                                  unsigned short* __restrict__ pnb,
                                                  float* __restrict__ P,
                                                  int* __restrict__ cnt) {
  __shared__ float Pl[C_N * D_N];
  __shared__ int cntl[C_N];
  const int tid = threadIdx.x;
  for (int i = tid; i < C_N * D_N; i += 256) Pl[i] = 0.f;
  if (tid < C_N) cntl[tid] = 0;
  __syncthreads();
  const int w = tid >> 6, lane = tid & 63;
  const int row0 = blockIdx.x * 256 + w * 64;
  for (int it = 0; it < 64; ++it) {
    const int row = row0 + it;
    const float4 v = *(const float4*)(pm + (size_t)row * D_N + lane * 4);
    float ss = v.x * v.x + v.y * v.y + v.z * v.z + v.w * v.w;
    ss = wave_reduce_sum(ss);
    const float r = 1.0f / fmaxf(sqrtf(ss), 1e-8f);
    const float a0 = v.x * r, a1 = v.y * r, a2 = v.z * r, a3 = v.w * r;
    ushort4 o;
    o.x = f2bf(a0); o.y = f2bf(a1); o.z = f2bf(a2); o.w = f2bf(a3);
    *(ushort4*)(pnb + (size_t)row * D_N + lane * 4) = o;
    const int cls = pl[row];
    float* base = Pl + cls * D_N + lane * 4;
    atomicAdd(base + 0, a0);
    atomicAdd(base + 1, a1);
    atomicAdd(base + 2, a2);
    atomicAdd(base + 3, a3);
    if (lane == 0) atomicAdd(&cntl[cls], 1);
  }
  __syncthreads();
  for (int i = tid; i < C_N * D_N; i += 256) atomicAdd(&P[i], Pl[i]);
  if (tid < C_N) atomicAdd(&cnt[tid], cntl[tid]);
}

// K2: normalize q rows -> f32 (qn) and bf16 (qnb). grid 2 blocks.
__global__ __launch_bounds__(256) void k_q_norm(const float* __restrict__ q,
                                                float* __restrict__ qn,
                                                unsigned short* __restrict__ qnb) {
  const int tid = threadIdx.x;
  const int w = tid >> 6, lane = tid & 63;
  const int row0 = blockIdx.x * 256 + w * 64;
  for (int it = 0; it < 64; ++it) {
    const int row = row0 + it;
    const float4 v = *(const float4*)(q + (size_t)row * D_N + lane * 4);
    float ss = v.x * v.x + v.y * v.y + v.z * v.z + v.w * v.w;
    ss = wave_reduce_sum(ss);
    const float r = 1.0f / fmaxf(sqrtf(ss), 1e-8f);
    float4 o4;
    o4.x = v.x * r; o4.y = v.y * r; o4.z = v.z * r; o4.w = v.w * r;
    *(float4*)(qn + (size_t)row * D_N + lane * 4) = o4;
    ushort4 o;
    o.x = f2bf(o4.x); o.y = f2bf(o4.y); o.z = f2bf(o4.z); o.w = f2bf(o4.w);
    *(ushort4*)(qnb + (size_t)row * D_N + lane * 4) = o;
  }
}

// K3: src (in-batch) branch. One block per row b. f32 exact-ish.
// Writes Zt[b] = Z_src (plain store; GEMM later atomicAdds Z_mem),
// Ss[b] = sum of (sc - smax) over same-label j != b, ns[b] = that count.
__global__ __launch_bounds__(256) void k_src(const float* __restrict__ qn,
                                             const int* __restrict__ labels,
                                             float* __restrict__ Zt,
                                             float* __restrict__ Ss,
                                             float* __restrict__ ns_) {
  __shared__ float4 qb4[64];
  __shared__ float sc[B_N];
  __shared__ float rmax[4];
  __shared__ float rz[4], rs[4], rn[4];
  const int b = blockIdx.x;
  const int tid = threadIdx.x, w = tid >> 6, lane = tid & 63;
  if (tid < 64) qb4[tid] = *(const float4*)(qn + (size_t)b * D_N + tid * 4);
  __syncthreads();
  const float4 u = qb4[lane];
  for (int jj = 0; jj < 128; ++jj) {
    const int j = w * 128 + jj;
    const float4 v = *(const float4*)(qn + (size_t)j * D_N + lane * 4);
    float d = v.x * u.x + v.y * u.y + v.z * u.z + v.w * u.w;
    d = wave_reduce_sum(d);
    if (lane == 0) sc[j] = d * TEMP_INV;
  }
  __syncthreads();
  float m = fmaxf(sc[tid], sc[tid + 256]);
  m = fmaxf(m, __shfl_xor(m, 32, 64));
  m = fmaxf(m, __shfl_xor(m, 16, 64));
  m = fmaxf(m, __shfl_xor(m, 8, 64));
  m = fmaxf(m, __shfl_xor(m, 4, 64));
  m = fmaxf(m, __shfl_xor(m, 2, 64));
  m = fmaxf(m, __shfl_xor(m, 1, 64));
  if (lane == 0) rmax[w] = m;
  __syncthreads();
  const float smax = fmaxf(fmaxf(rmax[0], rmax[1]), fmaxf(rmax[2], rmax[3]));
  const int lb = labels[b];
  float zacc = 0.f, sacc = 0.f, nacc = 0.f;
#pragma unroll
  for (int t = 0; t < 2; ++t) {
    const int j = tid + t * 256;
    if (j != b) {
      const float lg = sc[j] - smax;
      zacc += __builtin_amdgcn_exp2f(lg * LOG2E_F);
      if (labels[j] == lb) { sacc += lg; nacc += 1.f; }
    }
  }
  zacc = wave_reduce_sum(zacc);
  sacc = wave_reduce_sum(sacc);
  nacc = wave_reduce_sum(nacc);
  if (lane == 0) { rz[w] = zacc; rs[w] = sacc; rn[w] = nacc; }
  __syncthreads();
  if (tid == 0) {
    Zt[b] = rz[0] + rz[1] + rz[2] + rz[3];
    Ss[b] = rs[0] + rs[1] + rs[2] + rs[3];
    ns_[b] = rn[0] + rn[1] + rn[2] + rn[3];
  }
}

// K4: Z_mem via bf16 MFMA GEMM. 128x128 tile, BK=64, K=256 (4 steps), 4 waves.
// global_load_lds(16B) staging, T2 XOR-swizzle applied on SOURCE addresses
// (linear LDS dest) and on ds_read addresses (rule #21). Epilogue: exp2 +
// 16-lane shuffle reduce + LDS combine + global atomicAdd into Zt.
__global__ __launch_bounds__(256) void k_zmem(const unsigned short* __restrict__ qnb,
                                              const unsigned short* __restrict__ pnb,
                                              float* __restrict__ Zt) {
  __shared__ __align__(16) unsigned short As[128 * 64];
  __shared__ __align__(16) unsigned short Bs[128 * 64];
  __shared__ float zrow[128];
  const int tid = threadIdx.x;
  const int w = tid >> 6, lane = tid & 63;
  const int mt = blockIdx.x >> 2, bt = blockIdx.x & 3;
  const unsigned short* Ab = qnb + (size_t)(bt * 128) * D_N;
  const unsigned short* Bb = pnb + (size_t)(mt * 128) * D_N;
  if (tid < 128) zrow[tid] = 0.f;

  f32x4 acc[4][4];
#pragma unroll
  for (int mi = 0; mi < 4; ++mi)
#pragma unroll
    for (int ni = 0; ni < 4; ++ni)
      acc[mi][ni] = (f32x4){0.f, 0.f, 0.f, 0.f};

  const int wr = w >> 1, wc = w & 1;
  const int rsel = lane & 15, hi = lane >> 4;

  for (int ks = 0; ks < 4; ++ks) {
    const int kk = ks * 64;
#pragma unroll
    for (int i = 0; i < 4; ++i) {
      const int cbase = i * 256 + w * 64;       // wave-uniform chunk base
      const int c = cbase + lane;               // per-lane chunk (16B units)
      const int r = c >> 3;                     // tile row
      const int ss2 = (c & 7) ^ (r & 7);        // inverse-swizzled source slot
      __builtin_amdgcn_global_load_lds(
          (const __attribute__((address_space(1))) void*)(Ab + (size_t)r * D_N + kk + ss2 * 8),
          (__attribute__((address_space(3))) void*)(As + cbase * 8), 16, 0, 0);
      __builtin_amdgcn_global_load_lds(
          (const __attribute__((address_space(1))) void*)(Bb + (size_t)r * D_N + kk + ss2 * 8),
          (__attribute__((address_space(3))) void*)(Bs + cbase * 8), 16, 0, 0);
    }
    __syncthreads();
#pragma unroll
    for (int ksl = 0; ksl < 2; ++ksl) {
      const int sb = ksl * 4 + hi;              // logical 16B slot (k0/8)
      bf16x8 af[4], bfr[4];
#pragma unroll
      for (int mi = 0; mi < 4; ++mi) {
        const int r = wr * 64 + mi * 16 + rsel;
        af[mi] = *(const bf16x8*)((const char*)As + r * 128 + ((sb ^ (r & 7)) * 16));
      }
#pragma unroll
      for (int ni = 0; ni < 4; ++ni) {
        const int r = wc * 64 + ni * 16 + rsel;
        bfr[ni] = *(const bf16x8*)((const char*)Bs + r * 128 + ((sb ^ (r & 7)) * 16));
      }
#pragma unroll
      for (int mi = 0; mi < 4; ++mi)
#pragma unroll
        for (int ni = 0; ni < 4; ++ni)
          acc[mi][ni] = __builtin_amdgcn_mfma_f32_16x16x32_bf16(af[mi], bfr[ni], acc[mi][ni], 0, 0, 0);
    }
    __syncthreads();
  }

  // epilogue: Z partial = sum over this block's 128 m-columns of exp(logit)
#pragma unroll
  for (int mi = 0; mi < 4; ++mi) {
    float sv[4] = {0.f, 0.f, 0.f, 0.f};
#pragma unroll
    for (int ni = 0; ni < 4; ++ni)
#pragma unroll
      for (int r = 0; r < 4; ++r)
        sv[r] += __builtin_amdgcn_exp2f(acc[mi][ni][r] * K2C);
#pragma unroll
    for (int r = 0; r < 4; ++r) {
      float v = sv[r];
      v += __shfl_xor(v, 1, 64);
      v += __shfl_xor(v, 2, 64);
      v += __shfl_xor(v, 4, 64);
      v += __shfl_xor(v, 8, 64);
      if (rsel == 0) atomicAdd(&zrow[wr * 64 + mi * 16 + hi * 4 + r], v);
    }
  }
  __syncthreads();
  if (tid < 128) atomicAdd(&Zt[bt * 128 + tid], zrow[tid]);
}

// K5: loss = -mean_b [ (Ss[b] + qn[b].P[l[b]]/T) / (ns[b]+cnt[l[b]]) - log(Zt[b]) ]
__global__ __launch_bounds__(256) void k_final(const float* __restrict__ qn,
                                               const int* __restrict__ labels,
                                               const float* __restrict__ P,
                                               const int* __restrict__ cnt,
                                               const float* __restrict__ Zt,
                                               const float* __restrict__ Ss,
                                               const float* __restrict__ ns_,
                                               float* __restrict__ out) {
  __shared__ float part[4];
  const int tid = threadIdx.x, w = tid >> 6, lane = tid & 63;
  float accv = 0.f;
  for (int i = 0; i < 8; ++i) {
    const int b = blockIdx.x * 32 + w * 8 + i;
    const int cls = labels[b];
    const float4 v = *(const float4*)(qn + (size_t)b * D_N + lane * 4);
    const float4 p = *(const float4*)(P + (size_t)cls * D_N + lane * 4);
    float d = v.x * p.x + v.y * p.y + v.z * p.z + v.w * p.w;
    d = wave_reduce_sum(d);
    const float smem = d * TEMP_INV;
    const float ntot = ns_[b] + (float)cnt[cls];
    accv += (Ss[b] + smem) / ntot - logf(Zt[b]);
  }
  if (lane == 0) part[w] = accv;
  __syncthreads();
  if (tid == 0) {
    const float tot = part[0] + part[1] + part[2] + part[3];
    atomicAdd(out, -tot * (1.0f / (float)B_N));
  }
}

extern "C" void kernel_launch(void* const* d_in, const int* in_sizes, int n_in,
                              void* d_out, int out_size, void* d_ws, size_t ws_size,
                              hipStream_t stream) {
  const float* q = (const float*)d_in[0];
  const int* labels = (const int*)d_in[1];
  const float* pm = (const float*)d_in[2];
  const int* pl = (const int*)d_in[3];
  float* out = (float*)d_out;

  char* wsb = (char*)d_ws;
  // layout (bytes):
  // pnb  bf16 [65536][256]  @ 0          (33,554,432)
  // qn   f32  [512][256]    @ 33,554,432 (524,288)
  // qnb  bf16 [512][256]    @ 34,078,720 (262,144)
  // P    f32  [10][256]     @ 34,340,864 (10,240)
  // cnt  int  [10]          @ 34,351,104 (64 padded)
  // Zt   f32  [512]         @ 34,351,168 (2,048)
  // Ss   f32  [512]         @ 34,353,216 (2,048)
  // ns   f32  [512]         @ 34,355,264 (2,048)  -> end 34,357,312
  unsigned short* pnb = (unsigned short*)wsb;
  float* qn = (float*)(wsb + 33554432);
  unsigned short* qnb = (unsigned short*)(wsb + 34078720);
  float* P = (float*)(wsb + 34340864);
  int* cnt = (int*)(wsb + 34351104);
  float* Zt = (float*)(wsb + 34351168);
  float* Ss = (float*)(wsb + 34353216);
  float* ns_ = (float*)(wsb + 34355264);

  hipMemsetAsync(wsb + 34340864, 0, 16448, stream);
  hipMemsetAsync(d_out, 0, sizeof(float), stream);

  k_pro_norm<<<256, 256, 0, stream>>>(pm, pl, pnb, P, cnt);
  k_q_norm<<<2, 256, 0, stream>>>(q, qn, qnb);
  k_src<<<512, 256, 0, stream>>>(qn, labels, Zt, Ss, ns_);
  k_zmem<<<2048, 256, 0, stream>>>(qnb, pnb, Zt);
  k_final<<<16, 256, 0, stream>>>(qn, labels, P, cnt, Zt, Ss, ns_, out);
}

// Round 2
// 169.174 us; speedup vs baseline: 1.5252x; 1.5252x over previous
//
#include <hip/hip_runtime.h>
#include <stdint.h>
#include <math.h>

#define B_N 512
#define M_N 65536
#define D_N 256
#define C_N 10
#define TEMP_INV 14.285714285714286f   // 1/0.07
#define LOG2E_F 1.4426950408889634f
#define K2C (LOG2E_F * TEMP_INV)       // exp(x/T) = exp2(x*K2C)

typedef __attribute__((ext_vector_type(8))) __bf16 bf16x8;
typedef __attribute__((ext_vector_type(4))) float f32x4;

__device__ __forceinline__ unsigned short f2bf(float f) {
  unsigned int u = __float_as_uint(f);
  return (unsigned short)((u + 0x7FFFu + ((u >> 16) & 1u)) >> 16);  // RNE
}
__device__ __forceinline__ float bf2f(unsigned short s) {
  return __uint_as_float(((unsigned int)s) << 16);
}

__device__ __forceinline__ float wave_reduce_sum(float v) {
  v += __shfl_xor(v, 32, 64);
  v += __shfl_xor(v, 16, 64);
  v += __shfl_xor(v, 8, 64);
  v += __shfl_xor(v, 4, 64);
  v += __shfl_xor(v, 2, 64);
  v += __shfl_xor(v, 1, 64);
  return v;
}

// K1a: normalize pro_memory -> bf16. Quarter-wave rows: 16 lanes per row,
// 4 rows per wave-iteration, 2 iterations. 2048 blocks -> 32 waves/CU.
__global__ __launch_bounds__(256) void k_norm_pm(const float* __restrict__ pm,
                                                 unsigned short* __restrict__ pnb) {
  const int tid = threadIdx.x, w = tid >> 6, l = tid & 63;
  const int g = l >> 4, qs = l & 15;
  const int rbase = blockIdx.x * 32 + w * 8;
#pragma unroll
  for (int it = 0; it < 2; ++it) {
    const int r = rbase + it * 4 + g;
    const float* src = pm + (size_t)r * D_N;
    float4 v[4];
#pragma unroll
    for (int c = 0; c < 4; ++c) v[c] = *(const float4*)(src + qs * 4 + c * 64);
    float ss = 0.f;
#pragma unroll
    for (int c = 0; c < 4; ++c)
      ss += v[c].x * v[c].x + v[c].y * v[c].y + v[c].z * v[c].z + v[c].w * v[c].w;
    ss += __shfl_xor(ss, 1, 64);
    ss += __shfl_xor(ss, 2, 64);
    ss += __shfl_xor(ss, 4, 64);
    ss += __shfl_xor(ss, 8, 64);
    const float rv = 1.0f / fmaxf(sqrtf(ss), 1e-8f);
    unsigned short* dst = pnb + (size_t)r * D_N;
#pragma unroll
    for (int c = 0; c < 4; ++c) {
      ushort4 o;
      o.x = f2bf(v[c].x * rv); o.y = f2bf(v[c].y * rv);
      o.z = f2bf(v[c].z * rv); o.w = f2bf(v[c].w * rv);
      *(ushort4*)(dst + qs * 4 + c * 64) = o;
    }
  }
}

// K1b: per-class sum vectors P[10][256] and counts from bf16 pnb (L3-warm).
// LDS ds_add with stride-64 addressing (bank = lane%32, conflict-free-ish),
// then per-block global atomic flush (512 adds per address total).
__global__ __launch_bounds__(256) void k_class_sum(const unsigned short* __restrict__ pnb,
                                                   const int* __restrict__ pl,
                                                   float* __restrict__ P,
                                                   int* __restrict__ cnt) {
  __shared__ float Pl[C_N * D_N];
  __shared__ int cntl[C_N];
  const int tid = threadIdx.x, w = tid >> 6, l = tid & 63;
  for (int i = tid; i < C_N * D_N; i += 256) Pl[i] = 0.f;
  if (tid < C_N) cntl[tid] = 0;
  __syncthreads();
  const int rbase = blockIdx.x * 128 + w * 32;
#pragma unroll 4
  for (int it = 0; it < 32; ++it) {
    const int r = rbase + it;
    const int cls = pl[r];
    const unsigned short* src = pnb + (size_t)r * D_N;
    const float f0 = bf2f(src[l]);
    const float f1 = bf2f(src[l + 64]);
    const float f2 = bf2f(src[l + 128]);
    const float f3 = bf2f(src[l + 192]);
    float* base = Pl + cls * D_N;
    atomicAdd(base + l, f0);
    atomicAdd(base + l + 64, f1);
    atomicAdd(base + l + 128, f2);
    atomicAdd(base + l + 192, f3);
    if (l == 0) atomicAdd(&cntl[cls], 1);
  }
  __syncthreads();
  for (int i = tid; i < C_N * D_N; i += 256) atomicAdd(&P[i], Pl[i]);
  if (tid < C_N) atomicAdd(&cnt[tid], cntl[tid]);
}

// K2: normalize q -> f32 qn + bf16 qnb. 32 blocks, quarter-wave, 1 iter.
__global__ __launch_bounds__(256) void k_q_norm(const float* __restrict__ q,
                                                float* __restrict__ qn,
                                                unsigned short* __restrict__ qnb) {
  const int tid = threadIdx.x, w = tid >> 6, l = tid & 63;
  const int g = l >> 4, qs = l & 15;
  const int r = blockIdx.x * 16 + w * 4 + g;
  const float* src = q + (size_t)r * D_N;
  float4 v[4];
#pragma unroll
  for (int c = 0; c < 4; ++c) v[c] = *(const float4*)(src + qs * 4 + c * 64);
  float ss = 0.f;
#pragma unroll
  for (int c = 0; c < 4; ++c)
    ss += v[c].x * v[c].x + v[c].y * v[c].y + v[c].z * v[c].z + v[c].w * v[c].w;
  ss += __shfl_xor(ss, 1, 64);
  ss += __shfl_xor(ss, 2, 64);
  ss += __shfl_xor(ss, 4, 64);
  ss += __shfl_xor(ss, 8, 64);
  const float rv = 1.0f / fmaxf(sqrtf(ss), 1e-8f);
  float* dstf = qn + (size_t)r * D_N;
  unsigned short* dstb = qnb + (size_t)r * D_N;
#pragma unroll
  for (int c = 0; c < 4; ++c) {
    float4 o4;
    o4.x = v[c].x * rv; o4.y = v[c].y * rv; o4.z = v[c].z * rv; o4.w = v[c].w * rv;
    *(float4*)(dstf + qs * 4 + c * 64) = o4;
    ushort4 o;
    o.x = f2bf(o4.x); o.y = f2bf(o4.y); o.z = f2bf(o4.z); o.w = f2bf(o4.w);
    *(ushort4*)(dstb + qs * 4 + c * 64) = o;
  }
}

// K3: src branch via MFMA. 16 blocks (bt x jt of 128x128), same verified GEMM
// core as k_zmem. Epilogue: lg = acc/T - 1/T (smax == 1/T, diagonal dominates),
// exclude diag, accumulate Z_src / Ss / ns with label matching.
__global__ __launch_bounds__(256) void k_src(const unsigned short* __restrict__ qnb,
                                             const int* __restrict__ labels,
                                             float* __restrict__ Zt,
                                             float* __restrict__ Ss,
                                             float* __restrict__ ns_) {
  __shared__ __align__(16) unsigned short As[128 * 64];
  __shared__ __align__(16) unsigned short Bs[128 * 64];
  __shared__ int labR[128], labJ[128];
  __shared__ float zr[128], sr[128], nr[128];
  const int tid = threadIdx.x;
  const int w = tid >> 6, lane = tid & 63;
  const int bt = blockIdx.x >> 2, jt = blockIdx.x & 3;
  const unsigned short* Ab = qnb + (size_t)(bt * 128) * D_N;
  const unsigned short* Bb = qnb + (size_t)(jt * 128) * D_N;
  if (tid < 128) {
    labR[tid] = labels[bt * 128 + tid];
    labJ[tid] = labels[jt * 128 + tid];
    zr[tid] = 0.f; sr[tid] = 0.f; nr[tid] = 0.f;
  }

  f32x4 acc[4][4];
#pragma unroll
  for (int mi = 0; mi < 4; ++mi)
#pragma unroll
    for (int ni = 0; ni < 4; ++ni)
      acc[mi][ni] = (f32x4){0.f, 0.f, 0.f, 0.f};

  const int wr = w >> 1, wc = w & 1;
  const int rsel = lane & 15, hi = lane >> 4;

  for (int ks = 0; ks < 4; ++ks) {
    const int kk = ks * 64;
#pragma unroll
    for (int i = 0; i < 4; ++i) {
      const int cbase = i * 256 + w * 64;
      const int c = cbase + lane;
      const int r = c >> 3;
      const int ss2 = (c & 7) ^ (r & 7);
      __builtin_amdgcn_global_load_lds(
          (const __attribute__((address_space(1))) void*)(Ab + (size_t)r * D_N + kk + ss2 * 8),
          (__attribute__((address_space(3))) void*)(As + cbase * 8), 16, 0, 0);
      __builtin_amdgcn_global_load_lds(
          (const __attribute__((address_space(1))) void*)(Bb + (size_t)r * D_N + kk + ss2 * 8),
          (__attribute__((address_space(3))) void*)(Bs + cbase * 8), 16, 0, 0);
    }
    __syncthreads();
#pragma unroll
    for (int ksl = 0; ksl < 2; ++ksl) {
      const int sb = ksl * 4 + hi;
      bf16x8 af[4], bfr[4];
#pragma unroll
      for (int mi = 0; mi < 4; ++mi) {
        const int r = wr * 64 + mi * 16 + rsel;
        af[mi] = *(const bf16x8*)((const char*)As + r * 128 + ((sb ^ (r & 7)) * 16));
      }
#pragma unroll
      for (int ni = 0; ni < 4; ++ni) {
        const int r = wc * 64 + ni * 16 + rsel;
        bfr[ni] = *(const bf16x8*)((const char*)Bs + r * 128 + ((sb ^ (r & 7)) * 16));
      }
#pragma unroll
      for (int mi = 0; mi < 4; ++mi)
#pragma unroll
        for (int ni = 0; ni < 4; ++ni)
          acc[mi][ni] = __builtin_amdgcn_mfma_f32_16x16x32_bf16(af[mi], bfr[ni], acc[mi][ni], 0, 0, 0);
    }
    __syncthreads();
  }

#pragma unroll
  for (int mi = 0; mi < 4; ++mi) {
    float zs[4] = {0.f, 0.f, 0.f, 0.f};
    float sv[4] = {0.f, 0.f, 0.f, 0.f};
    float nv[4] = {0.f, 0.f, 0.f, 0.f};
#pragma unroll
    for (int ni = 0; ni < 4; ++ni) {
      const int j_loc = wc * 64 + ni * 16 + rsel;
      const int jg = jt * 128 + j_loc;
      const int lj = labJ[j_loc];
#pragma unroll
      for (int rg_ = 0; rg_ < 4; ++rg_) {
        const int r_loc = wr * 64 + mi * 16 + hi * 4 + rg_;
        const int rg = bt * 128 + r_loc;
        const float lg = acc[mi][ni][rg_] * TEMP_INV - TEMP_INV;
        if (rg != jg) {
          zs[rg_] += __builtin_amdgcn_exp2f(lg * LOG2E_F);
          if (labR[r_loc] == lj) { sv[rg_] += lg; nv[rg_] += 1.f; }
        }
      }
    }
#pragma unroll
    for (int rg_ = 0; rg_ < 4; ++rg_) {
      float z = zs[rg_], s = sv[rg_], n = nv[rg_];
      z += __shfl_xor(z, 1, 64); z += __shfl_xor(z, 2, 64);
      z += __shfl_xor(z, 4, 64); z += __shfl_xor(z, 8, 64);
      s += __shfl_xor(s, 1, 64); s += __shfl_xor(s, 2, 64);
      s += __shfl_xor(s, 4, 64); s += __shfl_xor(s, 8, 64);
      n += __shfl_xor(n, 1, 64); n += __shfl_xor(n, 2, 64);
      n += __shfl_xor(n, 4, 64); n += __shfl_xor(n, 8, 64);
      if (rsel == 0) {
        const int r_loc = wr * 64 + mi * 16 + hi * 4 + rg_;
        atomicAdd(&zr[r_loc], z);
        atomicAdd(&sr[r_loc], s);
        atomicAdd(&nr[r_loc], n);
      }
    }
  }
  __syncthreads();
  if (tid < 128) {
    atomicAdd(&Zt[bt * 128 + tid], zr[tid]);
    atomicAdd(&Ss[bt * 128 + tid], sr[tid]);
    atomicAdd(&ns_[bt * 128 + tid], nr[tid]);
  }
}

// K4: Z_mem via bf16 MFMA GEMM (unchanged verified core). atomicAdd into Zt.
__global__ __launch_bounds__(256) void k_zmem(const unsigned short* __restrict__ qnb,
                                              const unsigned short* __restrict__ pnb,
                                              float* __restrict__ Zt) {
  __shared__ __align__(16) unsigned short As[128 * 64];
  __shared__ __align__(16) unsigned short Bs[128 * 64];
  __shared__ float zrow[128];
  const int tid = threadIdx.x;
  const int w = tid >> 6, lane = tid & 63;
  const int mt = blockIdx.x >> 2, bt = blockIdx.x & 3;
  const unsigned short* Ab = qnb + (size_t)(bt * 128) * D_N;
  const unsigned short* Bb = pnb + (size_t)(mt * 128) * D_N;
  if (tid < 128) zrow[tid] = 0.f;

  f32x4 acc[4][4];
#pragma unroll
  for (int mi = 0; mi < 4; ++mi)
#pragma unroll
    for (int ni = 0; ni < 4; ++ni)
      acc[mi][ni] = (f32x4){0.f, 0.f, 0.f, 0.f};

  const int wr = w >> 1, wc = w & 1;
  const int rsel = lane & 15, hi = lane >> 4;

  for (int ks = 0; ks < 4; ++ks) {
    const int kk = ks * 64;
#pragma unroll
    for (int i = 0; i < 4; ++i) {
      const int cbase = i * 256 + w * 64;
      const int c = cbase + lane;
      const int r = c >> 3;
      const int ss2 = (c & 7) ^ (r & 7);
      __builtin_amdgcn_global_load_lds(
          (const __attribute__((address_space(1))) void*)(Ab + (size_t)r * D_N + kk + ss2 * 8),
          (__attribute__((address_space(3))) void*)(As + cbase * 8), 16, 0, 0);
      __builtin_amdgcn_global_load_lds(
          (const __attribute__((address_space(1))) void*)(Bb + (size_t)r * D_N + kk + ss2 * 8),
          (__attribute__((address_space(3))) void*)(Bs + cbase * 8), 16, 0, 0);
    }
    __syncthreads();
#pragma unroll
    for (int ksl = 0; ksl < 2; ++ksl) {
      const int sb = ksl * 4 + hi;
      bf16x8 af[4], bfr[4];
#pragma unroll
      for (int mi = 0; mi < 4; ++mi) {
        const int r = wr * 64 + mi * 16 + rsel;
        af[mi] = *(const bf16x8*)((const char*)As + r * 128 + ((sb ^ (r & 7)) * 16));
      }
#pragma unroll
      for (int ni = 0; ni < 4; ++ni) {
        const int r = wc * 64 + ni * 16 + rsel;
        bfr[ni] = *(const bf16x8*)((const char*)Bs + r * 128 + ((sb ^ (r & 7)) * 16));
      }
#pragma unroll
      for (int mi = 0; mi < 4; ++mi)
#pragma unroll
        for (int ni = 0; ni < 4; ++ni)
          acc[mi][ni] = __builtin_amdgcn_mfma_f32_16x16x32_bf16(af[mi], bfr[ni], acc[mi][ni], 0, 0, 0);
    }
    __syncthreads();
  }

#pragma unroll
  for (int mi = 0; mi < 4; ++mi) {
    float sv[4] = {0.f, 0.f, 0.f, 0.f};
#pragma unroll
    for (int ni = 0; ni < 4; ++ni)
#pragma unroll
      for (int r = 0; r < 4; ++r)
        sv[r] += __builtin_amdgcn_exp2f(acc[mi][ni][r] * K2C);
#pragma unroll
    for (int r = 0; r < 4; ++r) {
      float v = sv[r];
      v += __shfl_xor(v, 1, 64);
      v += __shfl_xor(v, 2, 64);
      v += __shfl_xor(v, 4, 64);
      v += __shfl_xor(v, 8, 64);
      if (rsel == 0) atomicAdd(&zrow[wr * 64 + mi * 16 + hi * 4 + r], v);
    }
  }
  __syncthreads();
  if (tid < 128) atomicAdd(&Zt[bt * 128 + tid], zrow[tid]);
}

// K5: loss. 128 blocks, 1 row per wave.
__global__ __launch_bounds__(256) void k_final(const float* __restrict__ qn,
                                               const int* __restrict__ labels,
                                               const float* __restrict__ P,
                                               const int* __restrict__ cnt,
                                               const float* __restrict__ Zt,
                                               const float* __restrict__ Ss,
                                               const float* __restrict__ ns_,
                                               float* __restrict__ out) {
  __shared__ float part[4];
  const int tid = threadIdx.x, w = tid >> 6, lane = tid & 63;
  const int b = blockIdx.x * 4 + w;
  const int cls = labels[b];
  const float4 v = *(const float4*)(qn + (size_t)b * D_N + lane * 4);
  const float4 p = *(const float4*)(P + (size_t)cls * D_N + lane * 4);
  float d = v.x * p.x + v.y * p.y + v.z * p.z + v.w * p.w;
  d = wave_reduce_sum(d);
  if (lane == 0) {
    const float smem = d * TEMP_INV;
    const float ntot = ns_[b] + (float)cnt[cls];
    part[w] = (Ss[b] + smem) / ntot - logf(Zt[b]);
  }
  __syncthreads();
  if (tid == 0)
    atomicAdd(out, -(part[0] + part[1] + part[2] + part[3]) * (1.0f / (float)B_N));
}

extern "C" void kernel_launch(void* const* d_in, const int* in_sizes, int n_in,
                              void* d_out, int out_size, void* d_ws, size_t ws_size,
                              hipStream_t stream) {
  const float* q = (const float*)d_in[0];
  const int* labels = (const int*)d_in[1];
  const float* pm = (const float*)d_in[2];
  const int* pl = (const int*)d_in[3];
  float* out = (float*)d_out;

  char* wsb = (char*)d_ws;
  unsigned short* pnb = (unsigned short*)wsb;              // 33,554,432 B
  float* qn = (float*)(wsb + 33554432);                    // 524,288 B
  unsigned short* qnb = (unsigned short*)(wsb + 34078720); // 262,144 B
  float* P = (float*)(wsb + 34340864);                     // 10,240 B
  int* cnt = (int*)(wsb + 34351104);                       // 64 B
  float* Zt = (float*)(wsb + 34351168);                    // 2,048 B
  float* Ss = (float*)(wsb + 34353216);                    // 2,048 B
  float* ns_ = (float*)(wsb + 34355264);                   // 2,048 B

  hipMemsetAsync(wsb + 34340864, 0, 16448, stream);
  hipMemsetAsync(d_out, 0, sizeof(float), stream);

  k_norm_pm<<<2048, 256, 0, stream>>>(pm, pnb);
  k_class_sum<<<512, 256, 0, stream>>>(pnb, pl, P, cnt);
  k_q_norm<<<32, 256, 0, stream>>>(q, qn, qnb);
  k_src<<<16, 256, 0, stream>>>(qnb, labels, Zt, Ss, ns_);
  k_zmem<<<2048, 256, 0, stream>>>(qnb, pnb, Zt);
  k_final<<<128, 256, 0, stream>>>(qn, labels, P, cnt, Zt, Ss, ns_, out);
}

// Round 3
// 109.120 us; speedup vs baseline: 2.3646x; 1.5503x over previous
//
#include <hip/hip_runtime.h>
#include <stdint.h>
#include <math.h>

#define B_N 512
#define M_N 65536
#define D_N 256
#define C_N 10
#define TEMP_INV 14.285714285714286f   // 1/0.07
#define LOG2E_F 1.4426950408889634f
#define K2C (LOG2E_F * TEMP_INV)       // exp(x/T) = exp2(x*K2C)

typedef __attribute__((ext_vector_type(8))) __bf16 bf16x8;
typedef __attribute__((ext_vector_type(4))) float f32x4;

__device__ __forceinline__ unsigned short f2bf(float f) {
  unsigned int u = __float_as_uint(f);
  return (unsigned short)((u + 0x7FFFu + ((u >> 16) & 1u)) >> 16);  // RNE
}
__device__ __forceinline__ float bf2f(unsigned short s) {
  return __uint_as_float(((unsigned int)s) << 16);
}

__device__ __forceinline__ float wave_reduce_sum(float v) {
  v += __shfl_xor(v, 32, 64);
  v += __shfl_xor(v, 16, 64);
  v += __shfl_xor(v, 8, 64);
  v += __shfl_xor(v, 4, 64);
  v += __shfl_xor(v, 2, 64);
  v += __shfl_xor(v, 1, 64);
  return v;
}

// K1a: normalize pro_memory -> bf16. Quarter-wave rows. Block 0 additionally
// zero-inits all small accumulators (P, cnt, Zt, Ss, ns, out) -- replaces the
// two hipMemsetAsync dispatches.
__global__ __launch_bounds__(256) void k_norm_pm(const float* __restrict__ pm,
                                                 unsigned short* __restrict__ pnb,
                                                 float* __restrict__ P,
                                                 int* __restrict__ cnt,
                                                 float* __restrict__ Zt,
                                                 float* __restrict__ Ss,
                                                 float* __restrict__ ns_,
                                                 float* __restrict__ out) {
  const int tid = threadIdx.x, w = tid >> 6, l = tid & 63;
  if (blockIdx.x == 0) {
    for (int i = tid; i < C_N * D_N; i += 256) P[i] = 0.f;
    if (tid < C_N) cnt[tid] = 0;
    for (int i = tid; i < B_N; i += 256) { Zt[i] = 0.f; Ss[i] = 0.f; ns_[i] = 0.f; }
    if (tid == 0) out[0] = 0.f;
  }
  const int g = l >> 4, qs = l & 15;
  const int rbase = blockIdx.x * 32 + w * 8;
#pragma unroll
  for (int it = 0; it < 2; ++it) {
    const int r = rbase + it * 4 + g;
    const float* src = pm + (size_t)r * D_N;
    float4 v[4];
#pragma unroll
    for (int c = 0; c < 4; ++c) v[c] = *(const float4*)(src + qs * 4 + c * 64);
    float ss = 0.f;
#pragma unroll
    for (int c = 0; c < 4; ++c)
      ss += v[c].x * v[c].x + v[c].y * v[c].y + v[c].z * v[c].z + v[c].w * v[c].w;
    ss += __shfl_xor(ss, 1, 64);
    ss += __shfl_xor(ss, 2, 64);
    ss += __shfl_xor(ss, 4, 64);
    ss += __shfl_xor(ss, 8, 64);
    const float rv = 1.0f / fmaxf(sqrtf(ss), 1e-8f);
    unsigned short* dst = pnb + (size_t)r * D_N;
#pragma unroll
    for (int c = 0; c < 4; ++c) {
      ushort4 o;
      o.x = f2bf(v[c].x * rv); o.y = f2bf(v[c].y * rv);
      o.z = f2bf(v[c].z * rv); o.w = f2bf(v[c].w * rv);
      *(ushort4*)(dst + qs * 4 + c * 64) = o;
    }
  }
}

// K1b-A: per-block class partial sums, NO atomics. 1024 blocks x 64 rows.
// Thread = dim d. Row class is wave-uniform -> uniform switch into 10 named
// register accumulators. Partials: part[blk][10][256], counts cntp[blk][10].
__global__ __launch_bounds__(256) void k_class_part(const unsigned short* __restrict__ pnb,
                                                    const int* __restrict__ pl,
                                                    float* __restrict__ part,
                                                    int* __restrict__ cntp) {
  const int tid = threadIdx.x;
  const int rbase = blockIdx.x * 64;
  float a0 = 0.f, a1 = 0.f, a2 = 0.f, a3 = 0.f, a4 = 0.f;
  float a5 = 0.f, a6 = 0.f, a7 = 0.f, a8 = 0.f, a9 = 0.f;
  int c0 = 0, c1 = 0, c2 = 0, c3 = 0, c4 = 0;
  int c5 = 0, c6 = 0, c7 = 0, c8 = 0, c9 = 0;
  for (int it = 0; it < 64; it += 8) {
    float v[8];
    int cl[8];
#pragma unroll
    for (int j = 0; j < 8; ++j) {
      const int r = rbase + it + j;
      cl[j] = pl[r];
      v[j] = bf2f(pnb[(size_t)r * D_N + tid]);
    }
#pragma unroll
    for (int j = 0; j < 8; ++j) {
      const float vv = v[j];
      switch (cl[j]) {
        case 0: a0 += vv; c0++; break;
        case 1: a1 += vv; c1++; break;
        case 2: a2 += vv; c2++; break;
        case 3: a3 += vv; c3++; break;
        case 4: a4 += vv; c4++; break;
        case 5: a5 += vv; c5++; break;
        case 6: a6 += vv; c6++; break;
        case 7: a7 += vv; c7++; break;
        case 8: a8 += vv; c8++; break;
        default: a9 += vv; c9++; break;
      }
    }
  }
  float* dst = part + (size_t)blockIdx.x * (C_N * D_N) + tid;
  dst[0] = a0; dst[256] = a1; dst[512] = a2; dst[768] = a3; dst[1024] = a4;
  dst[1280] = a5; dst[1536] = a6; dst[1792] = a7; dst[2048] = a8; dst[2304] = a9;
  if (tid == 0) {
    int* cd = cntp + blockIdx.x * C_N;
    cd[0] = c0; cd[1] = c1; cd[2] = c2; cd[3] = c3; cd[4] = c4;
    cd[5] = c5; cd[6] = c6; cd[7] = c7; cd[8] = c8; cd[9] = c9;
  }
}

// K1b-B: reduce partials. 40 blocks = 10 classes x 4 chunks of 256 blocks.
__global__ __launch_bounds__(256) void k_class_reduce(const float* __restrict__ part,
                                                      const int* __restrict__ cntp,
                                                      float* __restrict__ P,
                                                      int* __restrict__ cnt) {
  __shared__ int xs[4];
  const int c = blockIdx.x >> 2, q = blockIdx.x & 3;
  const int tid = threadIdx.x, w = tid >> 6, lane = tid & 63;
  float s = 0.f;
#pragma unroll 8
  for (int i = 0; i < 256; ++i)
    s += part[(size_t)(q * 256 + i) * (C_N * D_N) + c * 256 + tid];
  atomicAdd(&P[c * 256 + tid], s);
  int x = cntp[(q * 256 + tid) * C_N + c];
  x += __shfl_xor(x, 32, 64);
  x += __shfl_xor(x, 16, 64);
  x += __shfl_xor(x, 8, 64);
  x += __shfl_xor(x, 4, 64);
  x += __shfl_xor(x, 2, 64);
  x += __shfl_xor(x, 1, 64);
  if (lane == 0) xs[w] = x;
  __syncthreads();
  if (tid == 0) atomicAdd(&cnt[c], xs[0] + xs[1] + xs[2] + xs[3]);
}

// K2: normalize q -> f32 qn + bf16 qnb. 32 blocks, quarter-wave rows.
__global__ __launch_bounds__(256) void k_q_norm(const float* __restrict__ q,
                                                float* __restrict__ qn,
                                                unsigned short* __restrict__ qnb) {
  const int tid = threadIdx.x, w = tid >> 6, l = tid & 63;
  const int g = l >> 4, qs = l & 15;
  const int r = blockIdx.x * 16 + w * 4 + g;
  const float* src = q + (size_t)r * D_N;
  float4 v[4];
#pragma unroll
  for (int c = 0; c < 4; ++c) v[c] = *(const float4*)(src + qs * 4 + c * 64);
  float ss = 0.f;
#pragma unroll
  for (int c = 0; c < 4; ++c)
    ss += v[c].x * v[c].x + v[c].y * v[c].y + v[c].z * v[c].z + v[c].w * v[c].w;
  ss += __shfl_xor(ss, 1, 64);
  ss += __shfl_xor(ss, 2, 64);
  ss += __shfl_xor(ss, 4, 64);
  ss += __shfl_xor(ss, 8, 64);
  const float rv = 1.0f / fmaxf(sqrtf(ss), 1e-8f);
  float* dstf = qn + (size_t)r * D_N;
  unsigned short* dstb = qnb + (size_t)r * D_N;
#pragma unroll
  for (int c = 0; c < 4; ++c) {
    float4 o4;
    o4.x = v[c].x * rv; o4.y = v[c].y * rv; o4.z = v[c].z * rv; o4.w = v[c].w * rv;
    *(float4*)(dstf + qs * 4 + c * 64) = o4;
    ushort4 o;
    o.x = f2bf(o4.x); o.y = f2bf(o4.y); o.z = f2bf(o4.z); o.w = f2bf(o4.w);
    *(ushort4*)(dstb + qs * 4 + c * 64) = o;
  }
}

// K3: src branch via MFMA (verified core). lg = acc/T - 1/T (smax == 1/T).
__global__ __launch_bounds__(256) void k_src(const unsigned short* __restrict__ qnb,
                                             const int* __restrict__ labels,
                                             float* __restrict__ Zt,
                                             float* __restrict__ Ss,
                                             float* __restrict__ ns_) {
  __shared__ __align__(16) unsigned short As[128 * 64];
  __shared__ __align__(16) unsigned short Bs[128 * 64];
  __shared__ int labR[128], labJ[128];
  __shared__ float zr[128], sr[128], nr[128];
  const int tid = threadIdx.x;
  const int w = tid >> 6, lane = tid & 63;
  const int bt = blockIdx.x >> 2, jt = blockIdx.x & 3;
  const unsigned short* Ab = qnb + (size_t)(bt * 128) * D_N;
  const unsigned short* Bb = qnb + (size_t)(jt * 128) * D_N;
  if (tid < 128) {
    labR[tid] = labels[bt * 128 + tid];
    labJ[tid] = labels[jt * 128 + tid];
    zr[tid] = 0.f; sr[tid] = 0.f; nr[tid] = 0.f;
  }

  f32x4 acc[4][4];
#pragma unroll
  for (int mi = 0; mi < 4; ++mi)
#pragma unroll
    for (int ni = 0; ni < 4; ++ni)
      acc[mi][ni] = (f32x4){0.f, 0.f, 0.f, 0.f};

  const int wr = w >> 1, wc = w & 1;
  const int rsel = lane & 15, hi = lane >> 4;

  for (int ks = 0; ks < 4; ++ks) {
    const int kk = ks * 64;
#pragma unroll
    for (int i = 0; i < 4; ++i) {
      const int cbase = i * 256 + w * 64;
      const int c = cbase + lane;
      const int r = c >> 3;
      const int ss2 = (c & 7) ^ (r & 7);
      __builtin_amdgcn_global_load_lds(
          (const __attribute__((address_space(1))) void*)(Ab + (size_t)r * D_N + kk + ss2 * 8),
          (__attribute__((address_space(3))) void*)(As + cbase * 8), 16, 0, 0);
      __builtin_amdgcn_global_load_lds(
          (const __attribute__((address_space(1))) void*)(Bb + (size_t)r * D_N + kk + ss2 * 8),
          (__attribute__((address_space(3))) void*)(Bs + cbase * 8), 16, 0, 0);
    }
    __syncthreads();
#pragma unroll
    for (int ksl = 0; ksl < 2; ++ksl) {
      const int sb = ksl * 4 + hi;
      bf16x8 af[4], bfr[4];
#pragma unroll
      for (int mi = 0; mi < 4; ++mi) {
        const int r = wr * 64 + mi * 16 + rsel;
        af[mi] = *(const bf16x8*)((const char*)As + r * 128 + ((sb ^ (r & 7)) * 16));
      }
#pragma unroll
      for (int ni = 0; ni < 4; ++ni) {
        const int r = wc * 64 + ni * 16 + rsel;
        bfr[ni] = *(const bf16x8*)((const char*)Bs + r * 128 + ((sb ^ (r & 7)) * 16));
      }
#pragma unroll
      for (int mi = 0; mi < 4; ++mi)
#pragma unroll
        for (int ni = 0; ni < 4; ++ni)
          acc[mi][ni] = __builtin_amdgcn_mfma_f32_16x16x32_bf16(af[mi], bfr[ni], acc[mi][ni], 0, 0, 0);
    }
    __syncthreads();
  }

#pragma unroll
  for (int mi = 0; mi < 4; ++mi) {
    float zs[4] = {0.f, 0.f, 0.f, 0.f};
    float sv[4] = {0.f, 0.f, 0.f, 0.f};
    float nv[4] = {0.f, 0.f, 0.f, 0.f};
#pragma unroll
    for (int ni = 0; ni < 4; ++ni) {
      const int j_loc = wc * 64 + ni * 16 + rsel;
      const int jg = jt * 128 + j_loc;
      const int lj = labJ[j_loc];
#pragma unroll
      for (int rg_ = 0; rg_ < 4; ++rg_) {
        const int r_loc = wr * 64 + mi * 16 + hi * 4 + rg_;
        const int rg = bt * 128 + r_loc;
        const float lg = acc[mi][ni][rg_] * TEMP_INV - TEMP_INV;
        if (rg != jg) {
          zs[rg_] += __builtin_amdgcn_exp2f(lg * LOG2E_F);
          if (labR[r_loc] == lj) { sv[rg_] += lg; nv[rg_] += 1.f; }
        }
      }
    }
#pragma unroll
    for (int rg_ = 0; rg_ < 4; ++rg_) {
      float z = zs[rg_], s = sv[rg_], n = nv[rg_];
      z += __shfl_xor(z, 1, 64); z += __shfl_xor(z, 2, 64);
      z += __shfl_xor(z, 4, 64); z += __shfl_xor(z, 8, 64);
      s += __shfl_xor(s, 1, 64); s += __shfl_xor(s, 2, 64);
      s += __shfl_xor(s, 4, 64); s += __shfl_xor(s, 8, 64);
      n += __shfl_xor(n, 1, 64); n += __shfl_xor(n, 2, 64);
      n += __shfl_xor(n, 4, 64); n += __shfl_xor(n, 8, 64);
      if (rsel == 0) {
        const int r_loc = wr * 64 + mi * 16 + hi * 4 + rg_;
        atomicAdd(&zr[r_loc], z);
        atomicAdd(&sr[r_loc], s);
        atomicAdd(&nr[r_loc], n);
      }
    }
  }
  __syncthreads();
  if (tid < 128) {
    atomicAdd(&Zt[bt * 128 + tid], zr[tid]);
    atomicAdd(&Ss[bt * 128 + tid], sr[tid]);
    atomicAdd(&ns_[bt * 128 + tid], nr[tid]);
  }
}

// K4: Z_mem via bf16 MFMA GEMM (verified core). atomicAdd into Zt.
__global__ __launch_bounds__(256) void k_zmem(const unsigned short* __restrict__ qnb,
                                              const unsigned short* __restrict__ pnb,
                                              float* __restrict__ Zt) {
  __shared__ __align__(16) unsigned short As[128 * 64];
  __shared__ __align__(16) unsigned short Bs[128 * 64];
  __shared__ float zrow[128];
  const int tid = threadIdx.x;
  const int w = tid >> 6, lane = tid & 63;
  const int mt = blockIdx.x >> 2, bt = blockIdx.x & 3;
  const unsigned short* Ab = qnb + (size_t)(bt * 128) * D_N;
  const unsigned short* Bb = pnb + (size_t)(mt * 128) * D_N;
  if (tid < 128) zrow[tid] = 0.f;

  f32x4 acc[4][4];
#pragma unroll
  for (int mi = 0; mi < 4; ++mi)
#pragma unroll
    for (int ni = 0; ni < 4; ++ni)
      acc[mi][ni] = (f32x4){0.f, 0.f, 0.f, 0.f};

  const int wr = w >> 1, wc = w & 1;
  const int rsel = lane & 15, hi = lane >> 4;

  for (int ks = 0; ks < 4; ++ks) {
    const int kk = ks * 64;
#pragma unroll
    for (int i = 0; i < 4; ++i) {
      const int cbase = i * 256 + w * 64;
      const int c = cbase + lane;
      const int r = c >> 3;
      const int ss2 = (c & 7) ^ (r & 7);
      __builtin_amdgcn_global_load_lds(
          (const __attribute__((address_space(1))) void*)(Ab + (size_t)r * D_N + kk + ss2 * 8),
          (__attribute__((address_space(3))) void*)(As + cbase * 8), 16, 0, 0);
      __builtin_amdgcn_global_load_lds(
          (const __attribute__((address_space(1))) void*)(Bb + (size_t)r * D_N + kk + ss2 * 8),
          (__attribute__((address_space(3))) void*)(Bs + cbase * 8), 16, 0, 0);
    }
    __syncthreads();
#pragma unroll
    for (int ksl = 0; ksl < 2; ++ksl) {
      const int sb = ksl * 4 + hi;
      bf16x8 af[4], bfr[4];
#pragma unroll
      for (int mi = 0; mi < 4; ++mi) {
        const int r = wr * 64 + mi * 16 + rsel;
        af[mi] = *(const bf16x8*)((const char*)As + r * 128 + ((sb ^ (r & 7)) * 16));
      }
#pragma unroll
      for (int ni = 0; ni < 4; ++ni) {
        const int r = wc * 64 + ni * 16 + rsel;
        bfr[ni] = *(const bf16x8*)((const char*)Bs + r * 128 + ((sb ^ (r & 7)) * 16));
      }
#pragma unroll
      for (int mi = 0; mi < 4; ++mi)
#pragma unroll
        for (int ni = 0; ni < 4; ++ni)
          acc[mi][ni] = __builtin_amdgcn_mfma_f32_16x16x32_bf16(af[mi], bfr[ni], acc[mi][ni], 0, 0, 0);
    }
    __syncthreads();
  }

#pragma unroll
  for (int mi = 0; mi < 4; ++mi) {
    float sv[4] = {0.f, 0.f, 0.f, 0.f};
#pragma unroll
    for (int ni = 0; ni < 4; ++ni)
#pragma unroll
      for (int r = 0; r < 4; ++r)
        sv[r] += __builtin_amdgcn_exp2f(acc[mi][ni][r] * K2C);
#pragma unroll
    for (int r = 0; r < 4; ++r) {
      float v = sv[r];
      v += __shfl_xor(v, 1, 64);
      v += __shfl_xor(v, 2, 64);
      v += __shfl_xor(v, 4, 64);
      v += __shfl_xor(v, 8, 64);
      if (rsel == 0) atomicAdd(&zrow[wr * 64 + mi * 16 + hi * 4 + r], v);
    }
  }
  __syncthreads();
  if (tid < 128) atomicAdd(&Zt[bt * 128 + tid], zrow[tid]);
}

// K5: loss. 128 blocks, 1 row per wave.
__global__ __launch_bounds__(256) void k_final(const float* __restrict__ qn,
                                               const int* __restrict__ labels,
                                               const float* __restrict__ P,
                                               const int* __restrict__ cnt,
                                               const float* __restrict__ Zt,
                                               const float* __restrict__ Ss,
                                               const float* __restrict__ ns_,
                                               float* __restrict__ out) {
  __shared__ float part[4];
  const int tid = threadIdx.x, w = tid >> 6, lane = tid & 63;
  const int b = blockIdx.x * 4 + w;
  const int cls = labels[b];
  const float4 v = *(const float4*)(qn + (size_t)b * D_N + lane * 4);
  const float4 p = *(const float4*)(P + (size_t)cls * D_N + lane * 4);
  float d = v.x * p.x + v.y * p.y + v.z * p.z + v.w * p.w;
  d = wave_reduce_sum(d);
  if (lane == 0) {
    const float smem = d * TEMP_INV;
    const float ntot = ns_[b] + (float)cnt[cls];
    part[w] = (Ss[b] + smem) / ntot - logf(Zt[b]);
  }
  __syncthreads();
  if (tid == 0)
    atomicAdd(out, -(part[0] + part[1] + part[2] + part[3]) * (1.0f / (float)B_N));
}

extern "C" void kernel_launch(void* const* d_in, const int* in_sizes, int n_in,
                              void* d_out, int out_size, void* d_ws, size_t ws_size,
                              hipStream_t stream) {
  const float* q = (const float*)d_in[0];
  const int* labels = (const int*)d_in[1];
  const float* pm = (const float*)d_in[2];
  const int* pl = (const int*)d_in[3];
  float* out = (float*)d_out;

  char* wsb = (char*)d_ws;
  unsigned short* pnb = (unsigned short*)wsb;              // 33,554,432 B
  float* qn = (float*)(wsb + 33554432);                    // 524,288 B
  unsigned short* qnb = (unsigned short*)(wsb + 34078720); // 262,144 B
  float* P = (float*)(wsb + 34340864);                     // 10,240 B
  int* cnt = (int*)(wsb + 34351104);                       // 64 B
  float* Zt = (float*)(wsb + 34351168);                    // 2,048 B
  float* Ss = (float*)(wsb + 34353216);                    // 2,048 B
  float* ns_ = (float*)(wsb + 34355264);                   // 2,048 B
  float* part = (float*)(wsb + 34357312);                  // 1024*2560*4 = 10,485,760 B
  int* cntp = (int*)(wsb + 44843072);                      // 1024*10*4 = 40,960 B

  k_norm_pm<<<2048, 256, 0, stream>>>(pm, pnb, P, cnt, Zt, Ss, ns_, out);
  k_class_part<<<1024, 256, 0, stream>>>(pnb, pl, part, cntp);
  k_class_reduce<<<40, 256, 0, stream>>>(part, cntp, P, cnt);
  k_q_norm<<<32, 256, 0, stream>>>(q, qn, qnb);
  k_src<<<16, 256, 0, stream>>>(qnb, labels, Zt, Ss, ns_);
  k_zmem<<<2048, 256, 0, stream>>>(qnb, pnb, Zt);
  k_final<<<128, 256, 0, stream>>>(qn, labels, P, cnt, Zt, Ss, ns_, out);
}